// Round 1
// baseline (1229.610 us; speedup 1.0000x reference)
//
#include <hip/hip_runtime.h>

// Problem constants (fixed by reference)
#define NODES  131072   // N = B * NPG
#define CC     64       // in/out channels
#define HH     4        // heads
#define DD     64       // dim per head
#define HD     256      // H*D
#define BB     64       // graphs
#define NPG    2048     // nodes per graph
#define CHUNK  256      // nodes per block
#define CPG    (NPG/CHUNK)     // 8 chunks per graph
#define NBLK   (NODES/CHUNK)   // 512 blocks

__device__ __forceinline__ float wave_allreduce_sum(float v) {
#pragma unroll
    for (int off = 1; off < 64; off <<= 1)
        v += __shfl_xor(v, off, 64);
    return v;
}

// Phase 1: k = normalize(x @ Wk^T + bk); accumulate kv[b,h,d,c], ksum[b,h,d], vsum[b,c]
extern "C" __global__ __launch_bounds__(256, 2)
void k_phase1(const float* __restrict__ x,
              const float* __restrict__ Wk_w, const float* __restrict__ Wk_b,
              float* __restrict__ kv, float* __restrict__ ksum, float* __restrict__ vsum)
{
    __shared__ float4 x_l[CHUNK * 16];   // 256 nodes x 64 ch = 64 KB

    const int t     = threadIdx.x;       // t = h*64 + d
    const int b     = blockIdx.x / CPG;
    const int chunk = blockIdx.x % CPG;
    const size_t node0 = (size_t)b * NPG + (size_t)chunk * CHUNK;
    const int h    = t >> 6;
    const int lane = t & 63;             // = d

    // stage x tile (coalesced float4)
    const float4* xg = (const float4*)(x + node0 * CC);
#pragma unroll
    for (int i = 0; i < 16; ++i) x_l[t + i * 256] = xg[t + i * 256];

    // this thread's Wk row (r = t) in registers
    float Wrow[64];
    {
        const float4* wg = (const float4*)(Wk_w + (size_t)t * CC);
#pragma unroll
        for (int i = 0; i < 16; ++i) {
            float4 w4 = wg[i];
            Wrow[4*i+0] = w4.x; Wrow[4*i+1] = w4.y; Wrow[4*i+2] = w4.z; Wrow[4*i+3] = w4.w;
        }
    }
    const float bias = Wk_b[t];

    float kvacc[64];
#pragma unroll
    for (int i = 0; i < 64; ++i) kvacc[i] = 0.0f;
    float ksacc = 0.0f;

    __syncthreads();

    for (int nn = 0; nn < CHUNK; ++nn) {
        const float4* xr = &x_l[nn * 16];
        // projection: k[r] = bias + Wrow . x[nn]
        float kval = bias;
#pragma unroll
        for (int i = 0; i < 16; ++i) {
            float4 v = xr[i];
            kval = fmaf(Wrow[4*i+0], v.x, kval);
            kval = fmaf(Wrow[4*i+1], v.y, kval);
            kval = fmaf(Wrow[4*i+2], v.z, kval);
            kval = fmaf(Wrow[4*i+3], v.w, kval);
        }
        // L2 normalize across d (the 64 lanes of this wave = this head)
        float s = wave_allreduce_sum(kval * kval);
        kval *= rsqrtf(s);
        ksacc += kval;
        // prevent LDS-value CSE across the two unrolled loops (register pressure)
        asm volatile("" ::: "memory");
        // kv[d][c] += k[d] * x[c]   (c column held in registers)
#pragma unroll
        for (int i = 0; i < 16; ++i) {
            float4 v = xr[i];
            kvacc[4*i+0] = fmaf(kval, v.x, kvacc[4*i+0]);
            kvacc[4*i+1] = fmaf(kval, v.y, kvacc[4*i+1]);
            kvacc[4*i+2] = fmaf(kval, v.z, kvacc[4*i+2]);
            kvacc[4*i+3] = fmaf(kval, v.w, kvacc[4*i+3]);
        }
    }

    // merge partials
    atomicAdd(&ksum[(size_t)(b * HH + h) * DD + lane], ksacc);
    float* kvp = &kv[((size_t)(b * HH + h) * DD + lane) * CC];
#pragma unroll
    for (int c = 0; c < 64; ++c) atomicAdd(&kvp[c], kvacc[c]);

    if (t < 64) {  // vsum[b][c] = sum over nodes of x[n][c]
        float vs = 0.0f;
        const float* xs = (const float*)x_l;
        for (int nn = 0; nn < CHUNK; ++nn) vs += xs[nn * 64 + t];
        atomicAdd(&vsum[(size_t)b * CC + t], vs);
    }
}

// Phase 2: q = normalize(x @ Wq^T + bq); out = (q @ kv + vsum) / (q . ksum + n)
extern "C" __global__ __launch_bounds__(256, 2)
void k_phase2(const float* __restrict__ x,
              const float* __restrict__ Wq_w, const float* __restrict__ Wq_b,
              const int* __restrict__ n_nodes,
              const float* __restrict__ kv, const float* __restrict__ ksum,
              const float* __restrict__ vsum,
              float* __restrict__ out)
{
    __shared__ float4 x_l[CHUNK * 16];   // 64 KB

    const int t     = threadIdx.x;
    const int b     = blockIdx.x / CPG;
    const int chunk = blockIdx.x % CPG;
    const size_t node0 = (size_t)b * NPG + (size_t)chunk * CHUNK;
    const int h    = t >> 6;
    const int lane = t & 63;   // role 1: d for projection; role 2: c for output

    const float4* xg = (const float4*)(x + node0 * CC);
#pragma unroll
    for (int i = 0; i < 16; ++i) x_l[t + i * 256] = xg[t + i * 256];

    float Wrow[64];
    {
        const float4* wg = (const float4*)(Wq_w + (size_t)t * CC);
#pragma unroll
        for (int i = 0; i < 16; ++i) {
            float4 w4 = wg[i];
            Wrow[4*i+0] = w4.x; Wrow[4*i+1] = w4.y; Wrow[4*i+2] = w4.z; Wrow[4*i+3] = w4.w;
        }
    }
    const float bias = Wq_b[t];

    // kv column for (h, c=lane): kv[b][h][d][lane], d = 0..63
    float kvcol[64];
    {
        const float* kvp = &kv[((size_t)(b * HH + h) * DD) * CC + lane];
#pragma unroll
        for (int d = 0; d < 64; ++d) kvcol[d] = kvp[(size_t)d * CC];
    }
    const float ksr   = ksum[(size_t)(b * HH + h) * DD + lane];  // ksum[b][h][d=lane]
    const float vsr   = vsum[(size_t)b * CC + lane];             // vsum[b][c=lane]
    const float npg_f = (float)n_nodes[b];

    __syncthreads();

    float* outp = out + node0 * HD;
    for (int nn = 0; nn < CHUNK; ++nn) {
        const float4* xr = &x_l[nn * 16];
        float qv = bias;
#pragma unroll
        for (int i = 0; i < 16; ++i) {
            float4 v = xr[i];
            qv = fmaf(Wrow[4*i+0], v.x, qv);
            qv = fmaf(Wrow[4*i+1], v.y, qv);
            qv = fmaf(Wrow[4*i+2], v.z, qv);
            qv = fmaf(Wrow[4*i+3], v.w, qv);
        }
        float s = wave_allreduce_sum(qv * qv);
        qv *= rsqrtf(s);                                  // q[h][d=lane] normalized
        float den = wave_allreduce_sum(qv * ksr) + npg_f; // q . ksum + n  (all lanes)
        // numerator[c=lane] = sum_d q[d] * kv[d][lane]
        float num = 0.0f;
#pragma unroll
        for (int d = 0; d < 64; ++d)
            num = fmaf(__shfl(qv, d, 64), kvcol[d], num);
        outp[(size_t)nn * HD + t] = (num + vsr) / den;
    }
}

extern "C" void kernel_launch(void* const* d_in, const int* in_sizes, int n_in,
                              void* d_out, int out_size, void* d_ws, size_t ws_size,
                              hipStream_t stream) {
    const float* x     = (const float*)d_in[0];
    const float* Wq_w  = (const float*)d_in[1];
    const float* Wq_b  = (const float*)d_in[2];
    const float* Wk_w  = (const float*)d_in[3];
    const float* Wk_b  = (const float*)d_in[4];
    const int*   n_nodes = (const int*)d_in[5];
    float* out = (float*)d_out;

    float* kv   = (float*)d_ws;                       // [B][H][D][C] = 1,048,576 f32
    float* ksum = kv + (size_t)BB * HH * DD * CC;     // [B][H][D]    = 16,384 f32
    float* vsum = ksum + (size_t)BB * HH * DD;        // [B][C]       = 4,096 f32
    const size_t zero_bytes =
        ((size_t)BB * HH * DD * CC + (size_t)BB * HH * DD + (size_t)BB * CC) * sizeof(float);

    hipMemsetAsync(d_ws, 0, zero_bytes, stream);
    hipLaunchKernelGGL(k_phase1, dim3(NBLK), dim3(256), 0, stream,
                       x, Wk_w, Wk_b, kv, ksum, vsum);
    hipLaunchKernelGGL(k_phase2, dim3(NBLK), dim3(256), 0, stream,
                       x, Wq_w, Wq_b, n_nodes, kv, ksum, vsum, out);
}

// Round 2
// 255.782 us; speedup vs baseline: 4.8073x; 4.8073x over previous
//
#include <hip/hip_runtime.h>

#define BB    64
#define NPG   2048
#define TILE  128
#define NTILES (NPG / TILE)   // 16
#define XP    72              // xlds pitch (bf16 elems): 144B rows, 16B-aligned, banks spread
#define TP    136             // xt/kt pitch: 272B rows, 16B-aligned, banks spread
#define QP    104             // q pitch: 208B rows, 16B-aligned, banks spread

typedef short bf16x8 __attribute__((ext_vector_type(8)));
typedef float f32x4  __attribute__((ext_vector_type(4)));
typedef unsigned short u16x8 __attribute__((ext_vector_type(8)));
typedef unsigned short u16x4 __attribute__((ext_vector_type(4)));

__device__ __forceinline__ unsigned short f2b(float f) {
    unsigned int u = __float_as_uint(f);
    return (unsigned short)((u + 0x7FFFu + ((u >> 16) & 1u)) >> 16);  // RN-even
}

// ---------------------------------------------------------------------------
// Kernel A: per (b,h) block computes kv^T_ext[c'][d'] (80x80, f32) where
//   c',d' < 64 : kv^T[c][d] = sum_n x[n,c]*k~[n,d]   (k~ = normalized k)
//   c'=64 row  : ksum[d] ; d'=64 col : vsum[c] ; [64][64] = node count (2048)
// ---------------------------------------------------------------------------
extern "C" __global__ __launch_bounds__(512, 2)
void kv_kernel(const float* __restrict__ x,
               const float* __restrict__ Wk_w,
               const float* __restrict__ Wk_b,
               float* __restrict__ kvt)
{
    __shared__ __align__(16) unsigned short xlds[TILE * XP];  // x tile [n][c] bf16
    __shared__ __align__(16) unsigned short xt[80 * TP];      // x~^T   [c'][n] bf16 (+ones row 64)
    __shared__ __align__(16) unsigned short kt[80 * TP];      // k~^T   [d'][n] bf16 (+ones row 64)

    const int t  = threadIdx.x;
    const int l  = t & 63;
    const int w  = t >> 6;
    const int lr = l & 15;
    const int lg = l >> 4;
    const int bh = blockIdx.x;
    const int b  = bh >> 2;
    const int h  = bh & 3;

    // loop-invariant W A-fragments (projT: A = Wk rows of this head) + bias
    bf16x8 wf[4][2];
    float  bias[4][4];
#pragma unroll
    for (int mt = 0; mt < 4; ++mt) {
        const float* wp = Wk_w + (size_t)(h * 64 + mt * 16 + lr) * 64;
#pragma unroll
        for (int ks = 0; ks < 2; ++ks) {
            const float* p = wp + ks * 32 + lg * 8;
            bf16x8 f;
#pragma unroll
            for (int j = 0; j < 8; ++j) f[j] = (short)f2b(p[j]);
            wf[mt][ks] = f;
        }
#pragma unroll
        for (int i = 0; i < 4; ++i) bias[mt][i] = Wk_b[h * 64 + mt * 16 + 4 * lg + i];
    }

    // rows 64..79 of xt/kt: row 64 = ones (augmentation), 65..79 = zeros
    for (int idx = t; idx < 16 * TP; idx += 512) {
        int rr = idx / TP;
        int cc = idx - rr * TP;
        unsigned short v = (rr == 0 && cc < TILE) ? (unsigned short)0x3F80u : (unsigned short)0u;
        xt[(64 + rr) * TP + cc] = v;
        kt[(64 + rr) * TP + cc] = v;
    }

    // kv tile ownership: wave w owns tiles {w, w+8, w+16}, wave 0 also tile 24
    int cts[4], dts[4];
#pragma unroll
    for (int ti = 0; ti < 3; ++ti) {
        int tau = w + 8 * ti;
        int q5  = tau / 5;
        cts[ti] = q5;
        dts[ti] = tau - 5 * q5;
    }
    cts[3] = 4; dts[3] = 4;

    f32x4 kvacc[4] = {};

    const int cp = t & 63;          // transpose-fill: my column c'
    const int n0 = (t >> 6) * 16;   // and node sub-range

    const float4* xg0 = (const float4*)(x + (size_t)b * NPG * 64);

    for (int tt = 0; tt < NTILES; ++tt) {
        __syncthreads();  // previous iteration's kv GEMM done reading xt/kt/xlds

        // ---- stage x tile -> xlds (coalesced 16B/lane) ----
        const float4* xg = xg0 + (size_t)tt * TILE * 16;
#pragma unroll
        for (int j = 0; j < 4; ++j) {
            float4 v = xg[j * 512 + t];
            int n = j * 32 + (t >> 4);
            int c = (t & 15) * 4;
            u16x4 pv = { f2b(v.x), f2b(v.y), f2b(v.z), f2b(v.w) };
            *(u16x4*)&xlds[n * XP + c] = pv;
        }
        __syncthreads();

        // ---- transpose-fill xt[c'][n] from xlds (conflict-free lane remap) ----
        {
            u16x8 w0, w1;
#pragma unroll
            for (int k2 = 0; k2 < 8; ++k2) w0[k2] = xlds[(n0 + k2) * XP + cp];
#pragma unroll
            for (int k2 = 0; k2 < 8; ++k2) w1[k2] = xlds[(n0 + 8 + k2) * XP + cp];
            *(u16x8*)&xt[cp * TP + n0]     = w0;
            *(u16x8*)&xt[cp * TP + n0 + 8] = w1;
        }

        // ---- projT: k^T[r][n] = Wk_head . x^T  (this wave: 16 node-cols) ----
        f32x4 pacc[4] = {};
        const int ncol = w * 16 + lr;
#pragma unroll
        for (int ks = 0; ks < 2; ++ks) {
            bf16x8 xb = *(const bf16x8*)&xlds[ncol * XP + ks * 32 + lg * 8];
#pragma unroll
            for (int mt = 0; mt < 4; ++mt)
                pacc[mt] = __builtin_amdgcn_mfma_f32_16x16x32_bf16(wf[mt][ks], xb, pacc[mt], 0, 0, 0);
        }
        // bias + L2 norm over the 64 rows (lane-local + 2 shuffles across lg)
        float ss = 0.f;
#pragma unroll
        for (int mt = 0; mt < 4; ++mt)
#pragma unroll
            for (int i = 0; i < 4; ++i) {
                float v = pacc[mt][i] + bias[mt][i];
                pacc[mt][i] = v;
                ss = fmaf(v, v, ss);
            }
        ss += __shfl_xor(ss, 16, 64);
        ss += __shfl_xor(ss, 32, 64);
        float sc = rsqrtf(ss);
#pragma unroll
        for (int mt = 0; mt < 4; ++mt)
#pragma unroll
            for (int i = 0; i < 4; ++i)
                kt[(mt * 16 + 4 * lg + i) * TP + ncol] = f2b(pacc[mt][i] * sc);
        __syncthreads();

        // ---- kv GEMM: kvacc[c'tile][d'tile] += xt-frag x kt-frag over K=n ----
#pragma unroll
        for (int ks = 0; ks < 4; ++ks) {
            const int ko = ks * 32 + lg * 8;
            bf16x8 a0 = *(const bf16x8*)&xt[(cts[0] * 16 + lr) * TP + ko];
            bf16x8 b0 = *(const bf16x8*)&kt[(dts[0] * 16 + lr) * TP + ko];
            kvacc[0] = __builtin_amdgcn_mfma_f32_16x16x32_bf16(a0, b0, kvacc[0], 0, 0, 0);
            bf16x8 a1 = *(const bf16x8*)&xt[(cts[1] * 16 + lr) * TP + ko];
            bf16x8 b1 = *(const bf16x8*)&kt[(dts[1] * 16 + lr) * TP + ko];
            kvacc[1] = __builtin_amdgcn_mfma_f32_16x16x32_bf16(a1, b1, kvacc[1], 0, 0, 0);
            bf16x8 a2 = *(const bf16x8*)&xt[(cts[2] * 16 + lr) * TP + ko];
            bf16x8 b2 = *(const bf16x8*)&kt[(dts[2] * 16 + lr) * TP + ko];
            kvacc[2] = __builtin_amdgcn_mfma_f32_16x16x32_bf16(a2, b2, kvacc[2], 0, 0, 0);
            if (w == 0) {
                bf16x8 a3 = *(const bf16x8*)&xt[(64 + lr) * TP + ko];
                bf16x8 b3 = *(const bf16x8*)&kt[(64 + lr) * TP + ko];
                kvacc[3] = __builtin_amdgcn_mfma_f32_16x16x32_bf16(a3, b3, kvacc[3], 0, 0, 0);
            }
        }
    }

    // ---- store kv^T_ext (f32) ----
#pragma unroll
    for (int ti = 0; ti < 3; ++ti) {
        float* dst = kvt + ((size_t)bh * 80 + cts[ti] * 16 + 4 * lg) * 80 + dts[ti] * 16 + lr;
#pragma unroll
        for (int i = 0; i < 4; ++i) dst[i * 80] = kvacc[ti][i];
    }
    if (w == 0) {
        float* dst = kvt + ((size_t)bh * 80 + 64 + 4 * lg) * 80 + 64 + lr;
#pragma unroll
        for (int i = 0; i < 4; ++i) dst[i * 80] = kvacc[3][i];
    }
}

// ---------------------------------------------------------------------------
// Kernel B: per (b,h): q~ = normalize(x Wq^T + b); out_ext = q~_aug @ kv_ext
// (5 col-tiles: cols 0..63 numerator incl. +vsum via q~[n,64]=1; col 64 =
//  q.ksum + 2048 = denominator). out = num/den.
// ---------------------------------------------------------------------------
extern "C" __global__ __launch_bounds__(512, 2)
void out_kernel(const float* __restrict__ x,
                const float* __restrict__ Wq_w,
                const float* __restrict__ Wq_b,
                const float* __restrict__ kvt,
                float* __restrict__ out)
{
    __shared__ __align__(16) unsigned short xlds[TILE * XP];
    __shared__ __align__(16) unsigned short qlds[TILE * QP];  // q~ [n][d'] bf16, d'=64 ones, 65..95 zero

    const int t  = threadIdx.x;
    const int l  = t & 63;
    const int w  = t >> 6;
    const int lr = l & 15;
    const int lg = l >> 4;
    const int bh = blockIdx.x;
    const int b  = bh >> 2;
    const int h  = bh & 3;

    bf16x8 wf[4][2];
    float  bias[4][4];
#pragma unroll
    for (int mt = 0; mt < 4; ++mt) {
        const float* wp = Wq_w + (size_t)(h * 64 + mt * 16 + lr) * 64;
#pragma unroll
        for (int ks = 0; ks < 2; ++ks) {
            const float* p = wp + ks * 32 + lg * 8;
            bf16x8 f;
#pragma unroll
            for (int j = 0; j < 8; ++j) f[j] = (short)f2b(p[j]);
            wf[mt][ks] = f;
        }
#pragma unroll
        for (int i = 0; i < 4; ++i) bias[mt][i] = Wq_b[h * 64 + mt * 16 + 4 * lg + i];
    }

    // loop-invariant B-fragments from kv_ext: kvf[ct][ks]; element (k=d',col=c') = kvt[c'][d']
    bf16x8 kvf[5][3];
#pragma unroll
    for (int ct = 0; ct < 5; ++ct) {
        const float* kp = kvt + ((size_t)bh * 80 + ct * 16 + lr) * 80;
#pragma unroll
        for (int ks = 0; ks < 2; ++ks) {
            const float* p = kp + ks * 32 + lg * 8;
            bf16x8 f;
#pragma unroll
            for (int j = 0; j < 8; ++j) f[j] = (short)f2b(p[j]);
            kvf[ct][ks] = f;
        }
        bf16x8 f2 = {0, 0, 0, 0, 0, 0, 0, 0};   // k-step 2: only d'=64 is real
        if (lg == 0) f2[0] = (short)f2b(kp[64]);
        kvf[ct][2] = f2;
    }

    // q~ columns 64..95: col 64 = 1.0, rest 0 (written once, never overwritten)
    for (int idx = t; idx < TILE * 32; idx += 512) {
        int n  = idx >> 5;
        int cc = 64 + (idx & 31);
        qlds[n * QP + cc] = (cc == 64) ? (unsigned short)0x3F80u : (unsigned short)0u;
    }

    const float4* xg0 = (const float4*)(x + (size_t)b * NPG * 64);

    for (int tt = 0; tt < NTILES; ++tt) {
        __syncthreads();

        const float4* xg = xg0 + (size_t)tt * TILE * 16;
#pragma unroll
        for (int j = 0; j < 4; ++j) {
            float4 v = xg[j * 512 + t];
            int n = j * 32 + (t >> 4);
            int c = (t & 15) * 4;
            u16x4 pv = { f2b(v.x), f2b(v.y), f2b(v.z), f2b(v.w) };
            *(u16x4*)&xlds[n * XP + c] = pv;
        }
        __syncthreads();

        // projT q + norm
        f32x4 pacc[4] = {};
        const int ncol = w * 16 + lr;
#pragma unroll
        for (int ks = 0; ks < 2; ++ks) {
            bf16x8 xb = *(const bf16x8*)&xlds[ncol * XP + ks * 32 + lg * 8];
#pragma unroll
            for (int mt = 0; mt < 4; ++mt)
                pacc[mt] = __builtin_amdgcn_mfma_f32_16x16x32_bf16(wf[mt][ks], xb, pacc[mt], 0, 0, 0);
        }
        float ss = 0.f;
#pragma unroll
        for (int mt = 0; mt < 4; ++mt)
#pragma unroll
            for (int i = 0; i < 4; ++i) {
                float v = pacc[mt][i] + bias[mt][i];
                pacc[mt][i] = v;
                ss = fmaf(v, v, ss);
            }
        ss += __shfl_xor(ss, 16, 64);
        ss += __shfl_xor(ss, 32, 64);
        float sc = rsqrtf(ss);
        // write q~ [n][d] (transposed store; wave-local rows)
#pragma unroll
        for (int mt = 0; mt < 4; ++mt)
#pragma unroll
            for (int i = 0; i < 4; ++i)
                qlds[ncol * QP + mt * 16 + 4 * lg + i] = f2b(pacc[mt][i] * sc);
        __syncthreads();

        // numerator+denominator GEMM: this wave's 16 node-rows x 80 cols
        f32x4 nacc[5] = {};
#pragma unroll
        for (int ks = 0; ks < 3; ++ks) {
            bf16x8 qa = *(const bf16x8*)&qlds[(w * 16 + lr) * QP + ks * 32 + lg * 8];
#pragma unroll
            for (int ct = 0; ct < 5; ++ct)
                nacc[ct] = __builtin_amdgcn_mfma_f32_16x16x32_bf16(qa, kvf[ct][ks], nacc[ct], 0, 0, 0);
        }

        // epilogue: divide by col-64 (denominator) and store
        const int nrow = tt * TILE + w * 16;
        float* op = out + ((size_t)b * NPG + nrow) * 256 + h * 64;
#pragma unroll
        for (int i = 0; i < 4; ++i) {
            float den  = __shfl(nacc[4][i], (l & 48), 64);  // col 64 lives at lr==0 of same row-group
            float rden = 1.0f / den;
#pragma unroll
            for (int ct = 0; ct < 4; ++ct)
                op[(size_t)(4 * lg + i) * 256 + ct * 16 + lr] = nacc[ct][i] * rden;
        }
    }
}

extern "C" void kernel_launch(void* const* d_in, const int* in_sizes, int n_in,
                              void* d_out, int out_size, void* d_ws, size_t ws_size,
                              hipStream_t stream) {
    const float* x    = (const float*)d_in[0];
    const float* Wq_w = (const float*)d_in[1];
    const float* Wq_b = (const float*)d_in[2];
    const float* Wk_w = (const float*)d_in[3];
    const float* Wk_b = (const float*)d_in[4];
    float* out = (float*)d_out;
    float* kvt = (float*)d_ws;   // 256 * 80 * 80 f32 = 6.55 MB scratch

    hipLaunchKernelGGL(kv_kernel,  dim3(256), dim3(512), 0, stream, x, Wk_w, Wk_b, kvt);
    hipLaunchKernelGGL(out_kernel, dim3(256), dim3(512), 0, stream, x, Wq_w, Wq_b, kvt, out);
}